// Round 1
// 207.635 us; speedup vs baseline: 1.0104x; 1.0104x over previous
//
#include <hip/hip_runtime.h>
#include <hip/hip_bf16.h>

// CARAFE fp32 pipeline. x(4,256,64,64), Wc(64,256), bc(64), We(100,64,3,3),
// be(100) -> out(4,256,128,128). SF=2 K=5 G=1 CC=64 EK=3. All I/O fp32.
//
// ws layout (fp32 elements):
//   comp  [4][64][66*66]   zero-padded halo   @ 0        (1,115,136)
//   Wr    [ij4][cc64][q9][k pad28]            @ 1,115,136  (64,512)
//   logit [16384 px][100]  e = 4k+ij          @ 1,179,648  (1,638,400)
// total 2,818,048 floats = 11,272,192 B. Host-gated on ws_size; fallback =
// fused kernel (known-passing) if ws too small.
//
// Round 4 (this round): k2 rewritten. Old k2: 2048 x 1-wave blocks, inner-loop
// comp reads from GLOBAL (L2 latency on critical path), 2 waves/SIMD ->
// VALUBusy 30%, 61 us. New k2: 768 blocks x 256thr (4 ij-waves), comp halo
// tile staged in LDS once per block, per-wave private weight slices with
// 16B-aligned rows (ds_read_b128 broadcast), no main-loop barriers,
// 3 blocks/CU (12 waves/CU). Predicted ~16-20 us.

#define COMP_F 0
#define WR_F   1115136
#define LOG_F  1179648
#define WS_NEED 11272192ull
#define CSTR 4356  // 66*66 comp per-channel stride

// ---------------- K0: We(100,576) -> Wr[ij][cc][q][k28] ----------------
__global__ void k0_wr(const float* __restrict__ We, float* __restrict__ ws) {
    int tid = blockIdx.x * blockDim.x + threadIdx.x;
    if (tid >= 4 * 64 * 9 * 25) return;
    int k  = tid % 25;
    int q  = (tid / 25) % 9;
    int cc = (tid / 225) % 64;
    int ij = tid / 14400;
    ws[WR_F + (((size_t)(ij * 64 + cc) * 9) + q) * 28 + k] =
        We[(size_t)(4 * k + ij) * 576 + cc * 9 + q];
}

// ---------------- K1: 1x1 compressor 256->64, padded comp out ----------
// grid 2048 x 64thr: b = ccg*256 + pw  (same-pixel siblings share XCD L2).
__global__ __launch_bounds__(64) void k1_comp(const float* __restrict__ x,
                                              const float* __restrict__ Wc,
                                              const float* __restrict__ bc,
                                              float* __restrict__ ws) {
    int b   = blockIdx.x;
    int pw  = b & 255;
    int ccg = b >> 8;          // 0..7, wave-uniform
    int n = pw >> 6, h = pw & 63, w = threadIdx.x;
    int cc0 = ccg * 8;

    float acc[8];
#pragma unroll
    for (int u = 0; u < 8; ++u) acc[u] = 0.f;

    const float* xp = x + (size_t)n * 256 * 4096 + h * 64 + w;
#pragma unroll 4
    for (int c = 0; c < 256; ++c) {
        float xv = xp[(size_t)c * 4096];
#pragma unroll
        for (int u = 0; u < 8; ++u)
            acc[u] += xv * Wc[(cc0 + u) * 256 + c];  // uniform -> s_load
    }

    float* compb = ws + COMP_F + (size_t)(n * 64 + cc0) * CSTR;
#pragma unroll
    for (int u = 0; u < 8; ++u) {
        float* cb_ = compb + (size_t)u * CSTR;
        cb_[(h + 1) * 66 + (w + 1)] = acc[u] + bc[cc0 + u];
        // zero halo border (pad=1 of the 3x3 conv)
        if (w < 2) cb_[(h + 1) * 66 + (w ? 65 : 0)] = 0.f;
        if (h == 0)  { cb_[w] = 0.f;           if (w < 2) cb_[64 + w] = 0.f; }
        if (h == 63) { cb_[65 * 66 + w] = 0.f; if (w < 2) cb_[65 * 66 + 64 + w] = 0.f; }
    }
}

// ---------------- K2 v2: 3x3 encoder -> raw logits ----------------------
// grid 768 = kt*256 + tile; block 256 thr = 4 waves, wave = ij.
// kt splits k: {0..8}, {9..16}, {17..24}. comp tile in LDS (staged once);
// weights in per-wave LDS slices, 12-float rows (48B, 16B-aligned) so the
// kk-runs read as ds_read_b128 broadcast. No barriers in the cb loop: each
// wave writes/reads only its own slice (DS pipe is in-order per wave; an
// explicit lgkmcnt(0) fence covers cross-lane write->read inside the wave).
template <int K0, int KR>
__device__ void enc_body(const float* __restrict__ wr, const float* __restrict__ be,
                         float* __restrict__ logits, const float* __restrict__ compn,
                         float* compT, float* Wt, int n, int th, int tw) {
    const int tid  = threadIdx.x;
    const int lane = tid & 63;
    const int ij   = tid >> 6;              // wave id
    const int py = lane >> 3, pxx = lane & 7;
    const int h0 = th * 8, w0 = tw * 8;

    // stage comp halo tile: compT[c*100 + r*10 + q] = comp[c][h0+r][w0+q]
    for (int e = tid; e < 6400; e += 256) {
        int c = e / 100, rq = e % 100;
        compT[e] = compn[(size_t)c * CSTR + (h0 + rq / 10) * 66 + (w0 + rq % 10)];
    }
    __syncthreads();

    float acc[KR];
#pragma unroll
    for (int kk = 0; kk < KR; ++kk) acc[kk] = be[4 * (K0 + kk) + ij];

    float* wslice = Wt + ij * (144 * 12);            // 27648B/4 per wave
    const float* wsrc = wr + (size_t)ij * 64 * 252;  // this ij's weights

    for (int cb = 0; cb < 64; cb += 16) {
        // per-wave staging of own ij weights: row = c_*9+q, stride 12 floats
        for (int rowi = lane; rowi < 144; rowi += 64) {
            const float* s = wsrc + (size_t)(cb + rowi / 9) * 252 + (rowi % 9) * 28 + K0;
            float* d = wslice + rowi * 12;
#pragma unroll
            for (int kk = 0; kk < KR; ++kk) d[kk] = s[kk];
        }
        // fence: staging ds_writes complete before this wave's reads below
        asm volatile("s_waitcnt lgkmcnt(0)" ::: "memory");

#pragma unroll 2
        for (int c_ = 0; c_ < 16; ++c_) {
            const float* cp = compT + (cb + c_) * 100 + py * 10 + pxx;
            float cv[9];
#pragma unroll
            for (int dy = 0; dy < 3; ++dy)
#pragma unroll
                for (int dx = 0; dx < 3; ++dx)
                    cv[dy * 3 + dx] = cp[dy * 10 + dx];
            const float* wrow = wslice + c_ * 108;   // 9*12 floats per channel
#pragma unroll
            for (int q = 0; q < 9; ++q) {
                float v = cv[q];
#pragma unroll
                for (int kk = 0; kk < KR; ++kk)
                    acc[kk] += v * wrow[q * 12 + kk];  // uniform -> broadcast b128
            }
        }
    }

    float* lp = logits + ((size_t)(n * 4096 + (h0 + py) * 64 + (w0 + pxx))) * 100 + ij;
#pragma unroll
    for (int kk = 0; kk < KR; ++kk) lp[4 * (K0 + kk)] = acc[kk];
}

__global__ __launch_bounds__(256, 3) void k2_enc(const float* __restrict__ be,
                                                 float* __restrict__ ws) {
    __shared__ __align__(16) float compT[6400];        // 25600 B
    __shared__ __align__(16) float Wt[4 * 144 * 12];   // 27648 B -> 53248 total
    int b    = blockIdx.x;
    int tile = b & 255;                                 // low bits: same-tile
    int kt   = b >> 8;                                  // siblings same XCD
    int n = tile >> 6, th = (tile >> 3) & 7, tw = tile & 7;
    const float* compn  = ws + COMP_F + (size_t)n * 64 * CSTR;
    const float* wr     = ws + WR_F;
    float*       logits = ws + LOG_F;
    if (kt == 0)      enc_body<0, 9>(wr, be, logits, compn, compT, Wt, n, th, tw);
    else if (kt == 1) enc_body<9, 8>(wr, be, logits, compn, compT, Wt, n, th, tw);
    else              enc_body<17, 8>(wr, be, logits, compn, compT, Wt, n, th, tw);
}

// ---------------- K3: softmax (in-reg) + reassembly ---------------------
// grid 1024 x 256thr: b = cchunk*64 + tile. 16x16 px tile, 16-c chunk.
__global__ __launch_bounds__(256) void k3_out(const float* __restrict__ x,
                                              const float* __restrict__ ws,
                                              float* __restrict__ out) {
    __shared__ float xt[16 * 400];  // 20x20 halo x 16c, 25.6 KB
    int b      = blockIdx.x;
    int tile   = b & 63;
    int cchunk = b >> 6;
    int n = tile >> 4, ty0 = ((tile >> 2) & 3) * 16, tx0 = (tile & 3) * 16;
    int c0 = cchunk * 16;

    const float* xn = x + (size_t)(n * 256 + c0) * 4096;
    for (int e = threadIdx.x; e < 16 * 400; e += 256) {
        int c = e / 400, r = (e % 400) / 20, q = e % 20;
        int hh = ty0 + r - 2, ww = tx0 + q - 2;
        float v = 0.f;
        if (hh >= 0 && hh < 64 && ww >= 0 && ww < 64) v = xn[(size_t)c * 4096 + hh * 64 + ww];
        xt[e] = v;
    }

    int py = threadIdx.x >> 4, pxx = threadIdx.x & 15;
    int h = ty0 + py, w = tx0 + pxx;
    const float* lp = ws + LOG_F + (size_t)(n * 4096 + h * 64 + w) * 100;
    float4 mk[25];
#pragma unroll
    for (int t = 0; t < 25; ++t) mk[t] = ((const float4*)lp)[t];

    // softmax over the 25 taps, per ij component (recomputed per c-chunk: free)
    float4 mx = mk[0];
#pragma unroll
    for (int t = 1; t < 25; ++t) {
        mx.x = fmaxf(mx.x, mk[t].x); mx.y = fmaxf(mx.y, mk[t].y);
        mx.z = fmaxf(mx.z, mk[t].z); mx.w = fmaxf(mx.w, mk[t].w);
    }
    float4 sm = {0.f, 0.f, 0.f, 0.f};
#pragma unroll
    for (int t = 0; t < 25; ++t) {
        mk[t].x = __expf(mk[t].x - mx.x); sm.x += mk[t].x;
        mk[t].y = __expf(mk[t].y - mx.y); sm.y += mk[t].y;
        mk[t].z = __expf(mk[t].z - mx.z); sm.z += mk[t].z;
        mk[t].w = __expf(mk[t].w - mx.w); sm.w += mk[t].w;
    }
    float4 iv = {1.f / sm.x, 1.f / sm.y, 1.f / sm.z, 1.f / sm.w};
#pragma unroll
    for (int t = 0; t < 25; ++t) {
        mk[t].x *= iv.x; mk[t].y *= iv.y; mk[t].z *= iv.z; mk[t].w *= iv.w;
    }
    __syncthreads();

    for (int c = 0; c < 16; ++c) {
        const float* xc = xt + c * 400 + py * 20 + pxx;
        float a0 = 0.f, a1 = 0.f, a2 = 0.f, a3 = 0.f;
#pragma unroll
        for (int t = 0; t < 25; ++t) {
            float v = xc[(t / 5) * 20 + (t % 5)];
            a0 += v * mk[t].x; a1 += v * mk[t].y;
            a2 += v * mk[t].z; a3 += v * mk[t].w;
        }
        size_t ob = (((size_t)(n * 256 + c0 + c) * 128) + 2 * h) * 128 + 2 * w;
        float2 r0 = {a0, a1}, r1 = {a2, a3};
        *(float2*)(out + ob)       = r0;
        *(float2*)(out + ob + 128) = r1;
    }
}

// ---------------- Fallback: fused kernel, fp32-only ---------------------
__global__ __launch_bounds__(256) void k_fused(const float* __restrict__ x,
                                               const float* __restrict__ Wc,
                                               const float* __restrict__ bc,
                                               const float* __restrict__ We,
                                               const float* __restrict__ be,
                                               float* __restrict__ out) {
    __shared__ float compS[64 * 101];
    int n = blockIdx.x >> 6, tile = blockIdx.x & 63;
    int ty0 = (tile >> 3) * 8, tx0 = (tile & 7) * 8;
    const float* xn = x + (size_t)n * 256 * 4096;
    {
        int pa = threadIdx.x & 127;
        int ga = __builtin_amdgcn_readfirstlane(threadIdx.x >> 7);
        bool act = pa < 100;
        int ah = ty0 + pa / 10 - 1, aw = tx0 + pa % 10 - 1;
        bool inb = act && ah >= 0 && ah < 64 && aw >= 0 && aw < 64;
        int xoff = ah * 64 + aw;
        float acc[32];
#pragma unroll
        for (int i = 0; i < 32; ++i) acc[i] = 0.f;
        for (int c = 0; c < 256; ++c) {
            float xv = inb ? xn[(size_t)c * 4096 + xoff] : 0.f;
#pragma unroll
            for (int i = 0; i < 32; ++i) acc[i] += xv * Wc[(ga * 32 + i) * 256 + c];
        }
        if (act)
#pragma unroll
            for (int i = 0; i < 32; ++i) {
                int cc = ga * 32 + i;
                compS[cc * 101 + pa] = inb ? acc[i] + bc[cc] : 0.f;
            }
    }
    __syncthreads();
    int px = threadIdx.x & 63;
    int ij = __builtin_amdgcn_readfirstlane(threadIdx.x >> 6);
    int py = px >> 3, pxx = px & 7;
    int h = ty0 + py, w = tx0 + pxx;
    float m[25];
#pragma unroll
    for (int k = 0; k < 25; ++k) m[k] = be[4 * k + ij];
    for (int cc = 0; cc < 64; ++cc) {
        float cv[9];
#pragma unroll
        for (int dy = 0; dy < 3; ++dy)
#pragma unroll
            for (int dx = 0; dx < 3; ++dx)
                cv[dy * 3 + dx] = compS[cc * 101 + (py + dy) * 10 + (pxx + dx)];
        int base = cc * 9;
#pragma unroll
        for (int k = 0; k < 25; ++k) {
            int eb = (4 * k + ij) * 576 + base;
            float s = 0.f;
#pragma unroll
            for (int qb = 0; qb < 9; ++qb) s += cv[qb] * We[eb + qb];
            m[k] += s;
        }
    }
    float mxv = m[0];
#pragma unroll
    for (int k = 1; k < 25; ++k) mxv = fmaxf(mxv, m[k]);
    float ss = 0.f;
#pragma unroll
    for (int k = 0; k < 25; ++k) { m[k] = __expf(m[k] - mxv); ss += m[k]; }
    float inv = 1.f / ss;
#pragma unroll
    for (int k = 0; k < 25; ++k) m[k] *= inv;
    int offs[25];
    unsigned vm = 0;
#pragma unroll
    for (int t = 0; t < 25; ++t) {
        int hh = h + t / 5 - 2, ww = w + t % 5 - 2;
        bool v = hh >= 0 && hh < 64 && ww >= 0 && ww < 64;
        offs[t] = v ? hh * 64 + ww : 0;
        if (v) vm |= 1u << t;
    }
    size_t outp = ((size_t)n * 256 * 128 + (2 * h + (ij >> 1))) * 128 + (2 * w + (ij & 1));
    for (int c = 0; c < 256; ++c) {
        const float* xc = xn + (size_t)c * 4096;
        float sum = 0.f;
#pragma unroll
        for (int t = 0; t < 25; ++t) {
            float v = ((vm >> t) & 1u) ? xc[offs[t]] : 0.f;
            sum += v * m[t];
        }
        out[outp + (size_t)c * 16384] = sum;
    }
}

extern "C" void kernel_launch(void* const* d_in, const int* in_sizes, int n_in,
                              void* d_out, int out_size, void* d_ws, size_t ws_size,
                              hipStream_t stream) {
    const float* x  = (const float*)d_in[0];
    const float* Wc = (const float*)d_in[1];
    const float* bc = (const float*)d_in[2];
    const float* We = (const float*)d_in[3];
    const float* be = (const float*)d_in[4];
    float* out = (float*)d_out;

    if (ws_size >= WS_NEED && d_ws != nullptr) {
        float* ws = (float*)d_ws;
        hipLaunchKernelGGL(k0_wr,   dim3(225),  dim3(256), 0, stream, We, ws);
        hipLaunchKernelGGL(k1_comp, dim3(2048), dim3(64),  0, stream, x, Wc, bc, ws);
        hipLaunchKernelGGL(k2_enc,  dim3(768),  dim3(256), 0, stream, be, ws);
        hipLaunchKernelGGL(k3_out,  dim3(1024), dim3(256), 0, stream, x, ws, out);
    } else {
        hipLaunchKernelGGL(k_fused, dim3(256),  dim3(256), 0, stream,
                           x, Wc, bc, We, be, out);
    }
}

// Round 2
// 195.787 us; speedup vs baseline: 1.0715x; 1.0605x over previous
//
#include <hip/hip_runtime.h>
#include <hip/hip_bf16.h>

// CARAFE fp32 pipeline. x(4,256,64,64), Wc(64,256), bc(64), We(100,64,3,3),
// be(100) -> out(4,256,128,128). SF=2 K=5 G=1 CC=64 EK=3. All I/O fp32.
//
// ws layout (fp32 elements):
//   comp  [4][64][66*66]   zero-padded halo   @ 0          (1,115,136)
//   Wr2   [ij4][kt5][cc64][48]  q*5+kk packed @ 1,115,136  (61,440 of 64,512)
//   logit [16384 px][100]  e = 4k+ij          @ 1,179,648  (1,638,400)
// total 11,272,192 B. Host-gated on ws_size; fallback = fused kernel.
//
// Round 5 (this round): k2 v3. Round-4 post-mortem: weight reads via LDS
// saturated the per-CU DS pipe (~27 ds_read/c vs 81 FMA; VALUBusy 26%,
// bank-conflict 3.6M). v3 moves weights to the SMEM pipe (wave-uniform
// addresses -> s_load into SGPR, v_fmac takes SGPR operand), leaving only
// 9 cv ds_read_b32 per channel vs 45 FMAs. k split 5-ways (KR=5), grid
// 1280 x 4 ij-waves = 5 waves/SIMD (LDS 30.7KB -> 5 blocks/CU). comp tile
// row stride padded to 12 -> 2-way bank aliasing only (free).

#define COMP_F 0
#define WR_F   1115136
#define LOG_F  1179648
#define WS_NEED 11272192ull
#define CSTR 4356  // 66*66 comp per-channel stride

// ---------------- K0: We(100,576) -> Wr2[ij][kt][cc][48] ----------------
// Wr2 row (48 floats, 192B-aligned) holds w[q*5+kk] for one (ij,kt,cc).
__global__ void k0_wr(const float* __restrict__ We, float* __restrict__ ws) {
    int tid = blockIdx.x * blockDim.x + threadIdx.x;
    if (tid >= 4 * 5 * 64 * 45) return;
    int kk = tid % 5;
    int q  = (tid / 5) % 9;
    int cc = (tid / 45) % 64;
    int kt = (tid / 2880) % 5;
    int ij = tid / 14400;
    ws[WR_F + (size_t)(((ij * 5 + kt) * 64 + cc)) * 48 + q * 5 + kk] =
        We[(size_t)(4 * (kt * 5 + kk) + ij) * 576 + cc * 9 + q];
}

// ---------------- K1: 1x1 compressor 256->64, padded comp out ----------
// grid 2048 x 64thr: b = ccg*256 + pw  (same-pixel siblings share XCD L2).
__global__ __launch_bounds__(64) void k1_comp(const float* __restrict__ x,
                                              const float* __restrict__ Wc,
                                              const float* __restrict__ bc,
                                              float* __restrict__ ws) {
    int b   = blockIdx.x;
    int pw  = b & 255;
    int ccg = b >> 8;          // 0..7, wave-uniform
    int n = pw >> 6, h = pw & 63, w = threadIdx.x;
    int cc0 = ccg * 8;

    float acc[8];
#pragma unroll
    for (int u = 0; u < 8; ++u) acc[u] = 0.f;

    const float* xp = x + (size_t)n * 256 * 4096 + h * 64 + w;
#pragma unroll 4
    for (int c = 0; c < 256; ++c) {
        float xv = xp[(size_t)c * 4096];
#pragma unroll
        for (int u = 0; u < 8; ++u)
            acc[u] += xv * Wc[(cc0 + u) * 256 + c];  // uniform -> s_load
    }

    float* compb = ws + COMP_F + (size_t)(n * 64 + cc0) * CSTR;
#pragma unroll
    for (int u = 0; u < 8; ++u) {
        float* cb_ = compb + (size_t)u * CSTR;
        cb_[(h + 1) * 66 + (w + 1)] = acc[u] + bc[cc0 + u];
        // zero halo border (pad=1 of the 3x3 conv)
        if (w < 2) cb_[(h + 1) * 66 + (w ? 65 : 0)] = 0.f;
        if (h == 0)  { cb_[w] = 0.f;           if (w < 2) cb_[64 + w] = 0.f; }
        if (h == 63) { cb_[65 * 66 + w] = 0.f; if (w < 2) cb_[65 * 66 + 64 + w] = 0.f; }
    }
}

// ---------------- K2 v3: 3x3 encoder -> raw logits ----------------------
// grid 1280 = kt*256 + tile; block 256 thr = 4 ij-waves. kt gives k-range
// [kt*5, kt*5+5). comp 8x8 tile + 3x3 halo in LDS, row stride 12 (2-way
// bank aliasing = free). Weights read with wave-uniform addresses from
// global Wr2 -> s_load/SGPR (SMEM pipe), NOT the DS pipe. Per channel:
// 9 ds_read + 45 v_fmac (SGPR weight operand).
__global__ __launch_bounds__(256, 5) void k2_enc(const float* __restrict__ be,
                                                 float* __restrict__ ws) {
    __shared__ __align__(16) float compT[64 * 120];  // 30720 B
    int b    = blockIdx.x;
    int tile = b & 255;                              // low bits: same-tile
    int kt   = b >> 8;                               // 0..4, siblings same XCD
    int n = tile >> 6, th = (tile >> 3) & 7, tw = tile & 7;
    int h0 = th * 8, w0 = tw * 8;
    int tid = threadIdx.x;

    const float* compn = ws + COMP_F + (size_t)n * 64 * CSTR;
    // stage comp halo tile: compT[c*120 + r*12 + q] = comp[c][h0+r][w0+q]
    for (int e = tid; e < 6400; e += 256) {
        int c = e / 100, rq = e % 100, r = rq / 10, q = rq % 10;
        compT[c * 120 + r * 12 + q] =
            compn[(size_t)c * CSTR + (h0 + r) * 66 + (w0 + q)];
    }
    __syncthreads();

    int lane = tid & 63;
    int ij   = __builtin_amdgcn_readfirstlane(tid >> 6);  // force scalar
    int py = lane >> 3, pxx = lane & 7;

    const float* wb = ws + WR_F + (size_t)((ij * 5 + kt) * 64) * 48;

    float acc[5];
#pragma unroll
    for (int kk = 0; kk < 5; ++kk) acc[kk] = be[4 * (kt * 5 + kk) + ij];

#pragma unroll 2
    for (int c = 0; c < 64; ++c) {
        const float* cp = compT + c * 120 + py * 12 + pxx;
        float cv[9];
#pragma unroll
        for (int dy = 0; dy < 3; ++dy)
#pragma unroll
            for (int dx = 0; dx < 3; ++dx)
                cv[dy * 3 + dx] = cp[dy * 12 + dx];
        const float* w = wb + c * 48;                // uniform -> s_load
#pragma unroll
        for (int q = 0; q < 9; ++q) {
            float v = cv[q];
#pragma unroll
            for (int kk = 0; kk < 5; ++kk)
                acc[kk] += v * w[q * 5 + kk];        // v_fmac v, s, v
        }
    }

    float* lp = ws + LOG_F +
                (size_t)(n * 4096 + (h0 + py) * 64 + (w0 + pxx)) * 100 + ij;
#pragma unroll
    for (int kk = 0; kk < 5; ++kk) lp[4 * (kt * 5 + kk)] = acc[kk];
}

// ---------------- K3: softmax (in-reg) + reassembly ---------------------
// grid 1024 x 256thr: b = cchunk*64 + tile. 16x16 px tile, 16-c chunk.
__global__ __launch_bounds__(256) void k3_out(const float* __restrict__ x,
                                              const float* __restrict__ ws,
                                              float* __restrict__ out) {
    __shared__ float xt[16 * 400];  // 20x20 halo x 16c, 25.6 KB
    int b      = blockIdx.x;
    int tile   = b & 63;
    int cchunk = b >> 6;
    int n = tile >> 4, ty0 = ((tile >> 2) & 3) * 16, tx0 = (tile & 3) * 16;
    int c0 = cchunk * 16;

    const float* xn = x + (size_t)(n * 256 + c0) * 4096;
    for (int e = threadIdx.x; e < 16 * 400; e += 256) {
        int c = e / 400, r = (e % 400) / 20, q = e % 20;
        int hh = ty0 + r - 2, ww = tx0 + q - 2;
        float v = 0.f;
        if (hh >= 0 && hh < 64 && ww >= 0 && ww < 64) v = xn[(size_t)c * 4096 + hh * 64 + ww];
        xt[e] = v;
    }

    int py = threadIdx.x >> 4, pxx = threadIdx.x & 15;
    int h = ty0 + py, w = tx0 + pxx;
    const float* lp = ws + LOG_F + (size_t)(n * 4096 + h * 64 + w) * 100;
    float4 mk[25];
#pragma unroll
    for (int t = 0; t < 25; ++t) mk[t] = ((const float4*)lp)[t];

    // softmax over the 25 taps, per ij component (recomputed per c-chunk: free)
    float4 mx = mk[0];
#pragma unroll
    for (int t = 1; t < 25; ++t) {
        mx.x = fmaxf(mx.x, mk[t].x); mx.y = fmaxf(mx.y, mk[t].y);
        mx.z = fmaxf(mx.z, mk[t].z); mx.w = fmaxf(mx.w, mk[t].w);
    }
    float4 sm = {0.f, 0.f, 0.f, 0.f};
#pragma unroll
    for (int t = 0; t < 25; ++t) {
        mk[t].x = __expf(mk[t].x - mx.x); sm.x += mk[t].x;
        mk[t].y = __expf(mk[t].y - mx.y); sm.y += mk[t].y;
        mk[t].z = __expf(mk[t].z - mx.z); sm.z += mk[t].z;
        mk[t].w = __expf(mk[t].w - mx.w); sm.w += mk[t].w;
    }
    float4 iv = {1.f / sm.x, 1.f / sm.y, 1.f / sm.z, 1.f / sm.w};
#pragma unroll
    for (int t = 0; t < 25; ++t) {
        mk[t].x *= iv.x; mk[t].y *= iv.y; mk[t].z *= iv.z; mk[t].w *= iv.w;
    }
    __syncthreads();

    for (int c = 0; c < 16; ++c) {
        const float* xc = xt + c * 400 + py * 20 + pxx;
        float a0 = 0.f, a1 = 0.f, a2 = 0.f, a3 = 0.f;
#pragma unroll
        for (int t = 0; t < 25; ++t) {
            float v = xc[(t / 5) * 20 + (t % 5)];
            a0 += v * mk[t].x; a1 += v * mk[t].y;
            a2 += v * mk[t].z; a3 += v * mk[t].w;
        }
        size_t ob = (((size_t)(n * 256 + c0 + c) * 128) + 2 * h) * 128 + 2 * w;
        float2 r0 = {a0, a1}, r1 = {a2, a3};
        *(float2*)(out + ob)       = r0;
        *(float2*)(out + ob + 128) = r1;
    }
}

// ---------------- Fallback: fused kernel, fp32-only ---------------------
__global__ __launch_bounds__(256) void k_fused(const float* __restrict__ x,
                                               const float* __restrict__ Wc,
                                               const float* __restrict__ bc,
                                               const float* __restrict__ We,
                                               const float* __restrict__ be,
                                               float* __restrict__ out) {
    __shared__ float compS[64 * 101];
    int n = blockIdx.x >> 6, tile = blockIdx.x & 63;
    int ty0 = (tile >> 3) * 8, tx0 = (tile & 7) * 8;
    const float* xn = x + (size_t)n * 256 * 4096;
    {
        int pa = threadIdx.x & 127;
        int ga = __builtin_amdgcn_readfirstlane(threadIdx.x >> 7);
        bool act = pa < 100;
        int ah = ty0 + pa / 10 - 1, aw = tx0 + pa % 10 - 1;
        bool inb = act && ah >= 0 && ah < 64 && aw >= 0 && aw < 64;
        int xoff = ah * 64 + aw;
        float acc[32];
#pragma unroll
        for (int i = 0; i < 32; ++i) acc[i] = 0.f;
        for (int c = 0; c < 256; ++c) {
            float xv = inb ? xn[(size_t)c * 4096 + xoff] : 0.f;
#pragma unroll
            for (int i = 0; i < 32; ++i) acc[i] += xv * Wc[(ga * 32 + i) * 256 + c];
        }
        if (act)
#pragma unroll
            for (int i = 0; i < 32; ++i) {
                int cc = ga * 32 + i;
                compS[cc * 101 + pa] = inb ? acc[i] + bc[cc] : 0.f;
            }
    }
    __syncthreads();
    int px = threadIdx.x & 63;
    int ij = __builtin_amdgcn_readfirstlane(threadIdx.x >> 6);
    int py = px >> 3, pxx = px & 7;
    int h = ty0 + py, w = tx0 + pxx;
    float m[25];
#pragma unroll
    for (int k = 0; k < 25; ++k) m[k] = be[4 * k + ij];
    for (int cc = 0; cc < 64; ++cc) {
        float cv[9];
#pragma unroll
        for (int dy = 0; dy < 3; ++dy)
#pragma unroll
            for (int dx = 0; dx < 3; ++dx)
                cv[dy * 3 + dx] = compS[cc * 101 + (py + dy) * 10 + (pxx + dx)];
        int base = cc * 9;
#pragma unroll
        for (int k = 0; k < 25; ++k) {
            int eb = (4 * k + ij) * 576 + base;
            float s = 0.f;
#pragma unroll
            for (int qb = 0; qb < 9; ++qb) s += cv[qb] * We[eb + qb];
            m[k] += s;
        }
    }
    float mxv = m[0];
#pragma unroll
    for (int k = 1; k < 25; ++k) mxv = fmaxf(mxv, m[k]);
    float ss = 0.f;
#pragma unroll
    for (int k = 0; k < 25; ++k) { m[k] = __expf(m[k] - mxv); ss += m[k]; }
    float inv = 1.f / ss;
#pragma unroll
    for (int k = 0; k < 25; ++k) m[k] *= inv;
    int offs[25];
    unsigned vm = 0;
#pragma unroll
    for (int t = 0; t < 25; ++t) {
        int hh = h + t / 5 - 2, ww = w + t % 5 - 2;
        bool v = hh >= 0 && hh < 64 && ww >= 0 && ww < 64;
        offs[t] = v ? hh * 64 + ww : 0;
        if (v) vm |= 1u << t;
    }
    size_t outp = ((size_t)n * 256 * 128 + (2 * h + (ij >> 1))) * 128 + (2 * w + (ij & 1));
    for (int c = 0; c < 256; ++c) {
        const float* xc = xn + (size_t)c * 4096;
        float sum = 0.f;
#pragma unroll
        for (int t = 0; t < 25; ++t) {
            float v = ((vm >> t) & 1u) ? xc[offs[t]] : 0.f;
            sum += v * m[t];
        }
        out[outp + (size_t)c * 16384] = sum;
    }
}

extern "C" void kernel_launch(void* const* d_in, const int* in_sizes, int n_in,
                              void* d_out, int out_size, void* d_ws, size_t ws_size,
                              hipStream_t stream) {
    const float* x  = (const float*)d_in[0];
    const float* Wc = (const float*)d_in[1];
    const float* bc = (const float*)d_in[2];
    const float* We = (const float*)d_in[3];
    const float* be = (const float*)d_in[4];
    float* out = (float*)d_out;

    if (ws_size >= WS_NEED && d_ws != nullptr) {
        float* ws = (float*)d_ws;
        hipLaunchKernelGGL(k0_wr,   dim3(226),  dim3(256), 0, stream, We, ws);
        hipLaunchKernelGGL(k1_comp, dim3(2048), dim3(64),  0, stream, x, Wc, bc, ws);
        hipLaunchKernelGGL(k2_enc,  dim3(1280), dim3(256), 0, stream, be, ws);
        hipLaunchKernelGGL(k3_out,  dim3(1024), dim3(256), 0, stream, x, ws, out);
    } else {
        hipLaunchKernelGGL(k_fused, dim3(256),  dim3(256), 0, stream,
                           x, Wc, bc, We, be, out);
    }
}